// Round 13
// baseline (395.844 us; speedup 1.0000x reference)
//
#include <hip/hip_runtime.h>
#include <hip/hip_bf16.h>

#define B_ 1024
#define L_ 256
#define D_ 256
#define H_ 512
#define U_ 512
#define M_ (B_ * L_)

#define BM 128

typedef float f32x4 __attribute__((ext_vector_type(4)));
typedef short bf16x8 __attribute__((ext_vector_type(8)));

__device__ __forceinline__ short f2bf(float f) {
  unsigned u = __float_as_uint(f);
  u += 0x7fffu + ((u >> 16) & 1u);
  return (short)(u >> 16);
}

__device__ __forceinline__ float fast_tanh(float x) {
  float e = __expf(2.0f * x);
  return 1.0f - 2.0f * __builtin_amdgcn_rcpf(e + 1.0f);
}

// ---------------- prep: W1 [D,U] fp32 -> W1F fragment-major bf16 ----------------
// chunk c = nb*8 + kb (nb = u/16, kb = d/32); lane l of chunk c holds
// u = nb*16 + (l&15), d = kb*32 + (l>>4)*8 + j  ->  flat c*512 + l*8 + j.
__global__ void k_w1f(const float* __restrict__ W1, short* __restrict__ W1F) {
  int i = blockIdx.x * 256 + threadIdx.x;   // over 131072
  int jj = i & 7;
  int no = (i >> 3) & 15;
  int kc = (i >> 7) & 3;
  int kb = (i >> 9) & 7;
  int nb = i >> 12;
  int u = nb * 16 + no;
  int d = kb * 32 + kc * 8 + jj;
  W1F[i] = f2bf(W1[(size_t)d * U_ + u]);
}

// ---------------- projh[b,u] = hidden[b,:] @ W2[:,u] + b1[u] + b2[u] ----------------
__global__ void k_projh(const float* __restrict__ hidden, const float* __restrict__ W2,
                        const float* __restrict__ b1, const float* __restrict__ b2,
                        float* __restrict__ ph) {
  int u = blockIdx.x * 256 + threadIdx.x;
  int b0 = blockIdx.y * 8;
  float acc[8] = {0.f, 0.f, 0.f, 0.f, 0.f, 0.f, 0.f, 0.f};
  for (int h = 0; h < H_; ++h) {
    float w = W2[(size_t)h * U_ + u];
#pragma unroll
    for (int i = 0; i < 8; ++i) acc[i] = fmaf(hidden[(size_t)(b0 + i) * H_ + h], w, acc[i]);
  }
  float bias = b1[u] + b2[u];
#pragma unroll
  for (int i = 0; i < 8; ++i) ph[(size_t)(b0 + i) * U_ + u] = acc[i] + bias;
}

// ---------------- main: ZERO-LDS GEMM. 128x128 tile, 4 waves (2 wr x 2 wc) ----------------
// A-fragments direct from F (lane l: row = ..+(l&15), k = kt*32+(l>>4)*8+j); B-fragments
// direct from L2-resident W1F. No K-loop barriers. 4 sibling ntile-blocks per mtile
// combine via atomicAdd into memset logits (R12 bug: direct store dropped 3/4 of the u-sum).
__global__ __launch_bounds__(256, 3) void k_gemm(
    const float* __restrict__ F,    // [M_, D_] fp32
    const short* __restrict__ W1F,  // fragment-major bf16
    const float* __restrict__ ph,   // [B_, U_]
    const float* __restrict__ Wv,   // [U_]
    float* __restrict__ logits) {   // [M_], pre-zeroed
  __shared__ float csum[2][BM];     // 1 KB — the only LDS

  const int tid = threadIdx.x;
  const int lane = tid & 63;
  const int hi = lane >> 4;
  const int wid = tid >> 6;
  const int wr = wid >> 1, wc = wid & 1;
  const int tile = ((blockIdx.x & 7) << 10) | (blockIdx.x >> 3);  // XCD-chunked, bijective
  const int ntile = tile & 3;
  const int mtile = tile >> 2;
  const int m0 = mtile * BM;
  const int n0 = ntile * 128;
  const int b = m0 >> 8;

  // A: per mi, one base pointer; kt advances by 32 floats (offset-foldable)
  const float* ap[4];
#pragma unroll
  for (int mi = 0; mi < 4; ++mi)
    ap[mi] = F + (size_t)(m0 + wr * 64 + mi * 16 + (lane & 15)) * D_ + hi * 8;
  // B: per ni, one base; chunk(ni,kt) = (n0/16 + wc*4 + ni)*8 + kt, 1024B per chunk
  const short* bp[4];
#pragma unroll
  for (int ni = 0; ni < 4; ++ni)
    bp[ni] = W1F + ((size_t)((n0 >> 4) + wc * 4 + ni) * 8) * 512 + lane * 8;

  f32x4 acc[4][4];
  const f32x4 fz = {0.f, 0.f, 0.f, 0.f};
#pragma unroll
  for (int mi = 0; mi < 4; ++mi)
#pragma unroll
    for (int ni = 0; ni < 4; ++ni) acc[mi][ni] = fz;

#pragma unroll
  for (int kt = 0; kt < 8; ++kt) {
    bf16x8 af[4], bfr[4];
#pragma unroll
    for (int mi = 0; mi < 4; ++mi) {
      f32x4 lo = *(const f32x4*)(ap[mi] + kt * 32);
      f32x4 hi4 = *(const f32x4*)(ap[mi] + kt * 32 + 4);
      bf16x8 a;
#pragma unroll
      for (int j = 0; j < 4; ++j) { a[j] = f2bf(lo[j]); a[4 + j] = f2bf(hi4[j]); }
      af[mi] = a;
    }
#pragma unroll
    for (int ni = 0; ni < 4; ++ni)
      bfr[ni] = *(const bf16x8*)(bp[ni] + (size_t)kt * 512);
#pragma unroll
    for (int mi = 0; mi < 4; ++mi)
#pragma unroll
      for (int ni = 0; ni < 4; ++ni)
        acc[mi][ni] = __builtin_amdgcn_mfma_f32_16x16x32_bf16(af[mi], bfr[ni], acc[mi][ni], 0, 0, 0);
  }

  // epilogue: cs[mi][r] = sum_ni tanh(acc + ph[u]) * Wv[u]; u = n0+wc*64+ni*16+(lane&15)
  const float* phr = ph + (size_t)b * U_;
  float cs[4][4];
#pragma unroll
  for (int mi = 0; mi < 4; ++mi)
#pragma unroll
    for (int r = 0; r < 4; ++r) cs[mi][r] = 0.f;
#pragma unroll
  for (int ni = 0; ni < 4; ++ni) {
    int u = n0 + wc * 64 + ni * 16 + (lane & 15);
    float phv = phr[u];
    float wvv = Wv[u];
#pragma unroll
    for (int mi = 0; mi < 4; ++mi) {
#pragma unroll
      for (int r = 0; r < 4; ++r) {
        float x = acc[mi][ni][r] + phv;
        cs[mi][r] += fast_tanh(x) * wvv;
      }
    }
  }
  // reduce across the 16 u-lanes; C layout: m-row = hi*4 + r
#pragma unroll
  for (int mi = 0; mi < 4; ++mi) {
#pragma unroll
    for (int off = 1; off < 16; off <<= 1) {
#pragma unroll
      for (int r = 0; r < 4; ++r) cs[mi][r] += __shfl_xor(cs[mi][r], off);
    }
    if ((lane & 15) == 0) {
      int rloc = wr * 64 + mi * 16 + hi * 4;
#pragma unroll
      for (int r = 0; r < 4; ++r) csum[wc][rloc + r] = cs[mi][r];
    }
  }
  __syncthreads();
  // 4 sibling ntile-blocks contribute this mtile's quarter-sums
  if (tid < BM) atomicAdd(&logits[m0 + tid], csum[0][tid] + csum[1][tid]);
}

// ---------------- fused: softmax over L, then context[b,d] = sum_l w*F ----------------
__global__ void k_smctx(const float* __restrict__ logits, const float* __restrict__ F,
                        float* __restrict__ outw, float* __restrict__ ctx) {
  __shared__ float wl[L_];
  __shared__ f32x4 part[256];
  __shared__ float red[8];
  int b = blockIdx.x, t = threadIdx.x;
  float x = logits[(size_t)b * L_ + t];
  float m = x;
#pragma unroll
  for (int off = 32; off >= 1; off >>= 1) m = fmaxf(m, __shfl_xor(m, off));
  if ((t & 63) == 0) red[t >> 6] = m;
  __syncthreads();
  m = fmaxf(fmaxf(red[0], red[1]), fmaxf(red[2], red[3]));
  float e = __expf(x - m);
  float s = e;
#pragma unroll
  for (int off = 32; off >= 1; off >>= 1) s += __shfl_xor(s, off);
  if ((t & 63) == 0) red[4 + (t >> 6)] = s;
  __syncthreads();
  s = (red[4] + red[5]) + (red[6] + red[7]);
  float w = e / s;
  outw[(size_t)b * L_ + t] = w;
  wl[t] = w;
  __syncthreads();

  int lq = t >> 6, dq = t & 63;
  const f32x4* F4 = (const f32x4*)(F + (size_t)b * L_ * D_);
  f32x4 acc = {0.f, 0.f, 0.f, 0.f};
  for (int l = lq; l < L_; l += 4) acc += wl[l] * F4[l * 64 + dq];
  part[t] = acc;
  __syncthreads();
  if (lq == 0) {
    f32x4 r = (part[t] + part[t + 64]) + (part[t + 128] + part[t + 192]);
    ((f32x4*)ctx)[(size_t)b * 64 + dq] = r;
  }
}

extern "C" void kernel_launch(void* const* d_in, const int* in_sizes, int n_in,
                              void* d_out, int out_size, void* d_ws, size_t ws_size,
                              hipStream_t stream) {
  const float* F      = (const float*)d_in[0];
  const float* hidden = (const float*)d_in[1];
  const float* W1     = (const float*)d_in[2];
  const float* b1     = (const float*)d_in[3];
  const float* W2     = (const float*)d_in[4];
  const float* b2     = (const float*)d_in[5];
  const float* Wv     = (const float*)d_in[6];
  // d_in[7] = bv: shift-invariant under softmax, unused

  float* out_ctx = (float*)d_out;                 // [B,D]
  float* out_w   = out_ctx + (size_t)B_ * D_;     // [B,L]

  char* ws = (char*)d_ws;
  short* W1F    = (short*)ws;                     // 256 KB fragment-major bf16
  float* ph     = (float*)(ws + 262144);          // 2 MB fp32 [B,U]
  float* logits = (float*)(ws + 262144 + 2097152);// 1 MB fp32 [M_]

  hipMemsetAsync(logits, 0, (size_t)M_ * sizeof(float), stream);
  k_w1f<<<512, 256, 0, stream>>>(W1, W1F);
  k_projh<<<dim3(2, 128), 256, 0, stream>>>(hidden, W2, b1, b2, ph);
  k_gemm<<<8192, 256, 0, stream>>>(F, W1F, ph, Wv, logits);
  k_smctx<<<1024, 256, 0, stream>>>(logits, F, out_w, out_ctx);
}

// Round 14
// 295.790 us; speedup vs baseline: 1.3383x; 1.3383x over previous
//
#include <hip/hip_runtime.h>
#include <hip/hip_bf16.h>

#define B_ 1024
#define L_ 256
#define D_ 256
#define H_ 512
#define U_ 512
#define M_ (B_ * L_)

#define BM 128
#define BN 128
#define BK 64

typedef float f32x4 __attribute__((ext_vector_type(4)));
typedef short bf16x8 __attribute__((ext_vector_type(8)));
typedef short bf16x4 __attribute__((ext_vector_type(4)));

__device__ __forceinline__ short f2bf(float f) {
  unsigned u = __float_as_uint(f);
  u += 0x7fffu + ((u >> 16) & 1u);
  return (short)(u >> 16);
}

__device__ __forceinline__ void load16_g2l(const void* g, void* l) {
  __builtin_amdgcn_global_load_lds(
      (const __attribute__((address_space(1))) unsigned int*)g,
      (__attribute__((address_space(3))) unsigned int*)l, 16, 0, 0);
}

__device__ __forceinline__ float fast_tanh(float x) {
  float e = __expf(2.0f * x);
  return 1.0f - 2.0f * __builtin_amdgcn_rcpf(e + 1.0f);
}

// ---------------- prep: W1 [D,U] fp32 -> W1T [U,D] bf16 (R7-verified) ----------------
__global__ void k_w1t(const float* __restrict__ W1, short* __restrict__ W1T) {
  int idx = blockIdx.x * 256 + threadIdx.x;
  int u = idx >> 8;
  int d = idx & 255;
  W1T[idx] = f2bf(W1[(size_t)d * U_ + u]);
}

// ---------------- prep: F fp32 -> Fbf bf16 (memory-bound, coalesced) ----------------
__global__ void k_cast(const float* __restrict__ F, short* __restrict__ Fbf) {
  size_t i = ((size_t)blockIdx.x * 256 + threadIdx.x) * 4;
  const size_t stride = (size_t)4096 * 256 * 4;
#pragma unroll
  for (int it = 0; it < 16; ++it, i += stride) {
    f32x4 v = *(const f32x4*)(F + i);
    bf16x4 w;
#pragma unroll
    for (int j = 0; j < 4; ++j) w[j] = f2bf(v[j]);
    *(bf16x4*)(Fbf + i) = w;
  }
}

// ---------------- projh[b,u] = hidden[b,:] @ W2[:,u] + b1[u] + b2[u] ----------------
__global__ void k_projh(const float* __restrict__ hidden, const float* __restrict__ W2,
                        const float* __restrict__ b1, const float* __restrict__ b2,
                        float* __restrict__ ph) {
  int u = blockIdx.x * 256 + threadIdx.x;
  int b0 = blockIdx.y * 8;
  float acc[8] = {0.f, 0.f, 0.f, 0.f, 0.f, 0.f, 0.f, 0.f};
  for (int h = 0; h < H_; ++h) {
    float w = W2[(size_t)h * U_ + u];
#pragma unroll
    for (int i = 0; i < 8; ++i) acc[i] = fmaf(hidden[(size_t)(b0 + i) * H_ + h], w, acc[i]);
  }
  float bias = b1[u] + b2[u];
#pragma unroll
  for (int i = 0; i < 8; ++i) ph[(size_t)(b0 + i) * U_ + u] = acc[i] + bias;
}

// ---------------- FAST main: m97-style, BOTH operands via global_load_lds ----------------
// 128x128x64, LDS 32 KB single-buffered (A+B), 2 barriers/kt; 4-5 blocks/CU of TLP
// cover the vmcnt drains (m114). Zero staging VALU. XCD-chunked swizzle.
__global__ __launch_bounds__(256, 4) void k_gemm(
    const short* __restrict__ Fbf,  // [M_, D_] bf16
    const short* __restrict__ W1T,  // [U_, D_] bf16
    const float* __restrict__ ph,   // [B_, U_]
    const float* __restrict__ Wv,   // [U_]
    float* __restrict__ logits) {   // [M_], pre-zeroed
  __shared__ __align__(16) short As[BM * BK];   // 16 KB, swizzled 16B slots
  __shared__ __align__(16) short Bs[BN * BK];   // 16 KB, swizzled 16B slots

  const int tid = threadIdx.x;
  const int lane = tid & 63;
  const int hi = lane >> 4;
  const int wid = tid >> 6;
  const int wr = wid >> 1, wc = wid & 1;
  const int tile = ((blockIdx.x & 7) << 10) | (blockIdx.x >> 3);
  const int ntile = tile & 3;
  const int mtile = tile >> 2;
  const int m0 = mtile * BM;
  const int n0 = ntile * BN;
  const int b = m0 >> 8;

  const bf16x8* As8 = (const bf16x8*)As;
  const bf16x8* Bs8 = (const bf16x8*)Bs;

  // staging: slot s holds (row = s>>3, global chunk kq = (s&7)^(row&7)); 4 slots/thread each
  const short* agp[4];
  const short* bgp[4];
#pragma unroll
  for (int i = 0; i < 4; ++i) {
    int s = i * 256 + tid;
    int row = s >> 3;
    int kq = (s & 7) ^ (row & 7);
    agp[i] = Fbf + (size_t)(m0 + row) * D_ + kq * 8;
    bgp[i] = W1T + (size_t)(n0 + row) * D_ + kq * 8;
  }

  f32x4 acc[4][4];
  const f32x4 fz = {0.f, 0.f, 0.f, 0.f};
#pragma unroll
  for (int mi = 0; mi < 4; ++mi)
#pragma unroll
    for (int ni = 0; ni < 4; ++ni) acc[mi][ni] = fz;

  for (int kt = 0; kt < 4; ++kt) {
    if (kt) __syncthreads();   // WAR: previous tile consumed
#pragma unroll
    for (int i = 0; i < 4; ++i) {
      load16_g2l(agp[i], &As[(size_t)(i * 256 + tid) * 8]);
      agp[i] += BK;
    }
#pragma unroll
    for (int i = 0; i < 4; ++i) {
      load16_g2l(bgp[i], &Bs[(size_t)(i * 256 + tid) * 8]);
      bgp[i] += BK;
    }
    __syncthreads();           // drains vmcnt: tiles visible

#pragma unroll
    for (int kk = 0; kk < 2; ++kk) {
      bf16x8 af[4], bfr[4];
#pragma unroll
      for (int mi = 0; mi < 4; ++mi) {
        int rA = wr * 64 + mi * 16 + (lane & 15);
        af[mi] = As8[rA * 8 + ((kk * 4 + hi) ^ (rA & 7))];
      }
#pragma unroll
      for (int ni = 0; ni < 4; ++ni) {
        int nB = wc * 64 + ni * 16 + (lane & 15);
        bfr[ni] = Bs8[nB * 8 + ((kk * 4 + hi) ^ (nB & 7))];
      }
#pragma unroll
      for (int mi = 0; mi < 4; ++mi)
#pragma unroll
        for (int ni = 0; ni < 4; ++ni)
          acc[mi][ni] = __builtin_amdgcn_mfma_f32_16x16x32_bf16(af[mi], bfr[ni], acc[mi][ni], 0, 0, 0);
    }
  }

  // epilogue: x = acc + ph; partial logit = sum_u tanh(x)*Wv[u]; atomic combine
  const float* phr = ph + (size_t)b * U_;
  float phv[4], wvv[4];
#pragma unroll
  for (int ni = 0; ni < 4; ++ni) {
    int u = n0 + wc * 64 + ni * 16 + (lane & 15);
    phv[ni] = phr[u];
    wvv[ni] = Wv[u];
  }
#pragma unroll
  for (int mi = 0; mi < 4; ++mi) {
    float cs[4] = {0.f, 0.f, 0.f, 0.f};
#pragma unroll
    for (int ni = 0; ni < 4; ++ni) {
#pragma unroll
      for (int r = 0; r < 4; ++r) {
        float x = acc[mi][ni][r] + phv[ni];
        cs[r] += fast_tanh(x) * wvv[ni];
      }
    }
#pragma unroll
    for (int off = 1; off < 16; off <<= 1) {
#pragma unroll
      for (int r = 0; r < 4; ++r) cs[r] += __shfl_xor(cs[r], off);
    }
    if ((lane & 15) == 0) {
      int g = m0 + wr * 64 + mi * 16 + ((lane >> 4) << 2);
#pragma unroll
      for (int r = 0; r < 4; ++r) atomicAdd(&logits[g + r], cs[r]);
    }
  }
}

// ---------------- FALLBACK main: R7 verbatim (184 us measured) ----------------
__global__ __launch_bounds__(256, 3) void k_gemm_fb(
    const float* __restrict__ F, const short* __restrict__ W1T,
    const float* __restrict__ ph, const float* __restrict__ Wv,
    float* __restrict__ logits) {
  __shared__ __align__(16) short As[BM * BK];
  __shared__ __align__(16) short Bs[2][BN * BK];

  const int tid = threadIdx.x;
  const int lane = tid & 63;
  const int hi = lane >> 4;
  const int wid = tid >> 6;
  const int wr = wid >> 1, wc = wid & 1;
  const int tile = ((blockIdx.x & 7) << 10) | (blockIdx.x >> 3);
  const int ntile = tile & 3;
  const int mtile = tile >> 2;
  const int m0 = mtile * BM;
  const int n0 = ntile * BN;
  const int b = m0 >> 8;

  const bf16x8* As8 = (const bf16x8*)As;

  const float* agp[4];
  int aslot[4];
  const short* bgp[4];
#pragma unroll
  for (int i = 0; i < 4; ++i) {
    int s = i * 256 + tid;
    int arow = s >> 3;
    int akq = (s & 7) ^ (arow & 7);
    agp[i] = F + (size_t)(m0 + arow) * D_ + akq * 8;
    aslot[i] = s;
    bgp[i] = W1T + (size_t)(n0 + arow) * D_ + akq * 8;
  }

  f32x4 acc[4][4];
  const f32x4 fz = {0.f, 0.f, 0.f, 0.f};
#pragma unroll
  for (int mi = 0; mi < 4; ++mi)
#pragma unroll
    for (int ni = 0; ni < 4; ++ni) acc[mi][ni] = fz;

  f32x4 ar[4][2];
#pragma unroll
  for (int i = 0; i < 4; ++i) {
    ar[i][0] = *(const f32x4*)(agp[i]);
    ar[i][1] = *(const f32x4*)(agp[i] + 4);
    agp[i] += BK;
  }
#pragma unroll
  for (int i = 0; i < 4; ++i) {
    load16_g2l(bgp[i], &Bs[0][(size_t)(i * 256 + tid) * 8]);
    bgp[i] += BK;
  }

  for (int kt = 0; kt < 4; ++kt) {
    const bf16x8* BsC = (const bf16x8*)Bs[kt & 1];
    __syncthreads();
#pragma unroll
    for (int i = 0; i < 4; ++i) {
      bf16x8 w;
#pragma unroll
      for (int j = 0; j < 4; ++j) { w[j] = f2bf(ar[i][0][j]); w[4 + j] = f2bf(ar[i][1][j]); }
      ((bf16x8*)As)[aslot[i]] = w;
    }
    __syncthreads();
    if (kt < 3) {
#pragma unroll
      for (int i = 0; i < 4; ++i) {
        ar[i][0] = *(const f32x4*)(agp[i]);
        ar[i][1] = *(const f32x4*)(agp[i] + 4);
        agp[i] += BK;
      }
#pragma unroll
      for (int i = 0; i < 4; ++i) {
        load16_g2l(bgp[i], &Bs[(kt + 1) & 1][(size_t)(i * 256 + tid) * 8]);
        bgp[i] += BK;
      }
    }
#pragma unroll
    for (int kk = 0; kk < 2; ++kk) {
      bf16x8 af[4], bfr[4];
#pragma unroll
      for (int mi = 0; mi < 4; ++mi) {
        int rA = wr * 64 + mi * 16 + (lane & 15);
        af[mi] = As8[rA * 8 + ((kk * 4 + hi) ^ (rA & 7))];
      }
#pragma unroll
      for (int ni = 0; ni < 4; ++ni) {
        int nB = wc * 64 + ni * 16 + (lane & 15);
        bfr[ni] = BsC[nB * 8 + ((kk * 4 + hi) ^ (nB & 7))];
      }
#pragma unroll
      for (int mi = 0; mi < 4; ++mi)
#pragma unroll
        for (int ni = 0; ni < 4; ++ni)
          acc[mi][ni] = __builtin_amdgcn_mfma_f32_16x16x32_bf16(af[mi], bfr[ni], acc[mi][ni], 0, 0, 0);
    }
  }

  const float* phr = ph + (size_t)b * U_;
  float phv[4], wvv[4];
#pragma unroll
  for (int ni = 0; ni < 4; ++ni) {
    int u = n0 + wc * 64 + ni * 16 + (lane & 15);
    phv[ni] = phr[u];
    wvv[ni] = Wv[u];
  }
#pragma unroll
  for (int mi = 0; mi < 4; ++mi) {
    float cs[4] = {0.f, 0.f, 0.f, 0.f};
#pragma unroll
    for (int ni = 0; ni < 4; ++ni) {
#pragma unroll
      for (int r = 0; r < 4; ++r) {
        float x = acc[mi][ni][r] + phv[ni];
        cs[r] += fast_tanh(x) * wvv[ni];
      }
    }
#pragma unroll
    for (int off = 1; off < 16; off <<= 1) {
#pragma unroll
      for (int r = 0; r < 4; ++r) cs[r] += __shfl_xor(cs[r], off);
    }
    if ((lane & 15) == 0) {
      int g = m0 + wr * 64 + mi * 16 + ((lane >> 4) << 2);
#pragma unroll
      for (int r = 0; r < 4; ++r) atomicAdd(&logits[g + r], cs[r]);
    }
  }
}

// ---------------- fused: softmax over L, then context[b,d] = sum_l w*F (fp32 F!) ----------------
__global__ void k_smctx(const float* __restrict__ logits, const float* __restrict__ F,
                        float* __restrict__ outw, float* __restrict__ ctx) {
  __shared__ float wl[L_];
  __shared__ f32x4 part[256];
  __shared__ float red[8];
  int b = blockIdx.x, t = threadIdx.x;
  float x = logits[(size_t)b * L_ + t];
  float m = x;
#pragma unroll
  for (int off = 32; off >= 1; off >>= 1) m = fmaxf(m, __shfl_xor(m, off));
  if ((t & 63) == 0) red[t >> 6] = m;
  __syncthreads();
  m = fmaxf(fmaxf(red[0], red[1]), fmaxf(red[2], red[3]));
  float e = __expf(x - m);
  float s = e;
#pragma unroll
  for (int off = 32; off >= 1; off >>= 1) s += __shfl_xor(s, off);
  if ((t & 63) == 0) red[4 + (t >> 6)] = s;
  __syncthreads();
  s = (red[4] + red[5]) + (red[6] + red[7]);
  float w = e / s;
  outw[(size_t)b * L_ + t] = w;
  wl[t] = w;
  __syncthreads();

  int lq = t >> 6, dq = t & 63;
  const f32x4* F4 = (const f32x4*)(F + (size_t)b * L_ * D_);
  f32x4 acc = {0.f, 0.f, 0.f, 0.f};
  for (int l = lq; l < L_; l += 4) acc += wl[l] * F4[l * 64 + dq];
  part[t] = acc;
  __syncthreads();
  if (lq == 0) {
    f32x4 r = (part[t] + part[t + 64]) + (part[t + 128] + part[t + 192]);
    ((f32x4*)ctx)[(size_t)b * 64 + dq] = r;
  }
}

extern "C" void kernel_launch(void* const* d_in, const int* in_sizes, int n_in,
                              void* d_out, int out_size, void* d_ws, size_t ws_size,
                              hipStream_t stream) {
  const float* F      = (const float*)d_in[0];
  const float* hidden = (const float*)d_in[1];
  const float* W1     = (const float*)d_in[2];
  const float* b1     = (const float*)d_in[3];
  const float* W2     = (const float*)d_in[4];
  const float* b2     = (const float*)d_in[5];
  const float* Wv     = (const float*)d_in[6];
  // d_in[7] = bv: shift-invariant under softmax, unused

  float* out_ctx = (float*)d_out;                 // [B,D]
  float* out_w   = out_ctx + (size_t)B_ * D_;     // [B,L]

  char* ws = (char*)d_ws;
  short* W1T    = (short*)ws;                          // 256 KB
  float* ph     = (float*)(ws + 262144);               // 2 MB
  float* logits = (float*)(ws + 262144 + 2097152);     // 1 MB
  const size_t fb_off = 262144 + 2097152 + 1048576;    // 3,407,872 (16B-aligned)
  short* Fbf    = (short*)(ws + fb_off);               // 128 MB (fast path only)
  const bool fast = ws_size >= fb_off + (size_t)M_ * D_ * sizeof(short);

  hipMemsetAsync(logits, 0, (size_t)M_ * sizeof(float), stream);
  k_w1t<<<512, 256, 0, stream>>>(W1, W1T);
  k_projh<<<dim3(2, 128), 256, 0, stream>>>(hidden, W2, b1, b2, ph);
  if (fast) {
    k_cast<<<4096, 256, 0, stream>>>(F, Fbf);
    k_gemm<<<8192, 256, 0, stream>>>(Fbf, W1T, ph, Wv, logits);
  } else {
    k_gemm_fb<<<8192, 256, 0, stream>>>(F, W1T, ph, Wv, logits);
  }
  k_smctx<<<1024, 256, 0, stream>>>(logits, F, out_w, out_ctx);
}